// Round 11
// baseline (114.616 us; speedup 1.0000x reference)
//
#include <hip/hip_runtime.h>
#include <hip/hip_fp16.h>

#define NBINS 513
#define TFR   2048
#define NB    32
#define WIN   1024
#define HOP   256
#define PADT  384
#define OPB   524288
#define FR    16
#define TILES (TFR / FR)            /* 128 */
#define SPAN  (FR * HOP)            /* 4096 */
#define NPAIR 8                     /* frame pairs per block */
#define FSTRIDE 577                 /* uint2 per pair row, padded */
#define QIDX(e) ((e) + ((e) >> 3))  /* b64 bank pad */
#define C45 0.70710678118654752f
#define TWOPI_1024 0.0061359231515425649f
/* scale: 1/512 (IFFT) * 2/3 (interior envelope 1.5 pre-divided) */
#define SSC   (1.0f / 512.0f * 2.0f / 3.0f)
#define CDLT  0.99998117528260114f   /* cos(2*pi/1024) */
#define SDLT  0.00613588464915448f   /* sin(2*pi/1024) */

__device__ __forceinline__ float2 cadd(float2 a, float2 b){ return make_float2(a.x+b.x, a.y+b.y); }
__device__ __forceinline__ float2 csub(float2 a, float2 b){ return make_float2(a.x-b.x, a.y-b.y); }
__device__ __forceinline__ float2 cmul(float2 a, float2 b){ return make_float2(a.x*b.x - a.y*b.y, a.x*b.y + a.y*b.x); }

// pair element: (reA,reB) in .x as half2, (imA,imB) in .y as half2
__device__ __forceinline__ uint2 pack_pair(float2 zA, float2 zB) {
    __half2 re = __floats2half2_rn(zA.x, zB.x);
    __half2 im = __floats2half2_rn(zA.y, zB.y);
    uint2 r;
    r.x = *(const unsigned int*)&re;
    r.y = *(const unsigned int*)&im;
    return r;
}
__device__ __forceinline__ void unpack_pair(uint2 v, float2& zA, float2& zB) {
    float2 fr = __half22float2(*(const __half2*)&v.x);
    float2 fi = __half22float2(*(const __half2*)&v.y);
    zA = make_float2(fr.x, fi.x);
    zB = make_float2(fr.y, fi.y);
}

#define BFLY8(u0,u1,u2,u3,u4,u5,u6,u7, v0,v1,v2,v3,v4,v5,v6,v7)            \
    float2 s0=cadd(u0,u4), t0=csub(u0,u4);                                  \
    float2 s1=cadd(u1,u5), t1=csub(u1,u5);                                  \
    float2 s2=cadd(u2,u6), t2=csub(u2,u6);                                  \
    float2 s3=cadd(u3,u7), t3=csub(u3,u7);                                  \
    t1 = make_float2(C45*(t1.x - t1.y),  C45*(t1.x + t1.y));                \
    t2 = make_float2(-t2.y, t2.x);                                          \
    t3 = make_float2(-C45*(t3.x + t3.y), C45*(t3.x - t3.y));                \
    float2 p0=cadd(s0,s2), p2=csub(s0,s2);                                  \
    float2 p1=cadd(s1,s3), p3=csub(s1,s3); p3 = make_float2(-p3.y, p3.x);   \
    float2 q0=cadd(t0,t2), q2=csub(t0,t2);                                  \
    float2 q1=cadd(t1,t3), q3=csub(t1,t3); q3 = make_float2(-q3.y, q3.x);   \
    v0=cadd(p0,p1); v4=csub(p0,p1);                                         \
    v2=cadd(p2,p3); v6=csub(p2,p3);                                         \
    v1=cadd(q0,q1); v5=csub(q0,q1);                                         \
    v3=cadd(q2,q3); v7=csub(q2,q3);

// Paired radix-8 DIF stage: one b64 element = 2 frames. i in [0,64).
// L=64,8: aligned write-back. L=1: B-plane written rotated by +2 in q so
// that slot j holds (zA[n(j)], zB[(n(j)+128) mod 512]).
template<int L>
__device__ __forceinline__ void fft_stage_pk(uint2* __restrict__ row,
                                             const float2* __restrict__ ph, int i)
{
    const int k    = i & (L - 1);
    const int base = ((i & ~(L - 1)) << 3) + k;
    uint2 w0 = row[QIDX(base + 0*L)];
    uint2 w1v = row[QIDX(base + 1*L)];
    uint2 w2 = row[QIDX(base + 2*L)];
    uint2 w3 = row[QIDX(base + 3*L)];
    uint2 w4 = row[QIDX(base + 4*L)];
    uint2 w5 = row[QIDX(base + 5*L)];
    uint2 w6 = row[QIDX(base + 6*L)];
    uint2 w7 = row[QIDX(base + 7*L)];
    float2 uA0,uA1,uA2,uA3,uA4,uA5,uA6,uA7;
    float2 uB0,uB1,uB2,uB3,uB4,uB5,uB6,uB7;
    unpack_pair(w0, uA0, uB0); unpack_pair(w1v, uA1, uB1);
    unpack_pair(w2, uA2, uB2); unpack_pair(w3, uA3, uB3);
    unpack_pair(w4, uA4, uB4); unpack_pair(w5, uA5, uB5);
    unpack_pair(w6, uA6, uB6); unpack_pair(w7, uA7, uB7);

    float2 vA0,vA1,vA2,vA3,vA4,vA5,vA6,vA7;
    float2 vB0,vB1,vB2,vB3,vB4,vB5,vB6,vB7;
    { BFLY8(uA0,uA1,uA2,uA3,uA4,uA5,uA6,uA7, vA0,vA1,vA2,vA3,vA4,vA5,vA6,vA7) }
    { BFLY8(uB0,uB1,uB2,uB3,uB4,uB5,uB6,uB7, vB0,vB1,vB2,vB3,vB4,vB5,vB6,vB7) }

    if constexpr (L > 1) {
        const float2 tw = ph[k * (128 / L)];   // idx <= 126
        float2 wq = tw;
        vA1 = cmul(vA1, wq); vB1 = cmul(vB1, wq);
        wq = cmul(wq, tw); vA2 = cmul(vA2, wq); vB2 = cmul(vB2, wq);
        wq = cmul(wq, tw); vA3 = cmul(vA3, wq); vB3 = cmul(vB3, wq);
        wq = cmul(wq, tw); vA4 = cmul(vA4, wq); vB4 = cmul(vB4, wq);
        wq = cmul(wq, tw); vA5 = cmul(vA5, wq); vB5 = cmul(vB5, wq);
        wq = cmul(wq, tw); vA6 = cmul(vA6, wq); vB6 = cmul(vB6, wq);
        wq = cmul(wq, tw); vA7 = cmul(vA7, wq); vB7 = cmul(vB7, wq);
        row[QIDX(base + 0*L)] = pack_pair(vA0, vB0);
        row[QIDX(base + 1*L)] = pack_pair(vA1, vB1);
        row[QIDX(base + 2*L)] = pack_pair(vA2, vB2);
        row[QIDX(base + 3*L)] = pack_pair(vA3, vB3);
        row[QIDX(base + 4*L)] = pack_pair(vA4, vB4);
        row[QIDX(base + 5*L)] = pack_pair(vA5, vB5);
        row[QIDX(base + 6*L)] = pack_pair(vA6, vB6);
        row[QIDX(base + 7*L)] = pack_pair(vA7, vB7);
    } else {
        // B rotated: slot q gets vB_{(q+2)&7}
        row[QIDX(base + 0)] = pack_pair(vA0, vB2);
        row[QIDX(base + 1)] = pack_pair(vA1, vB3);
        row[QIDX(base + 2)] = pack_pair(vA2, vB4);
        row[QIDX(base + 3)] = pack_pair(vA3, vB5);
        row[QIDX(base + 4)] = pack_pair(vA4, vB6);
        row[QIDX(base + 5)] = pack_pair(vA5, vB7);
        row[QIDX(base + 6)] = pack_pair(vA6, vB0);
        row[QIDX(base + 7)] = pack_pair(vA7, vB1);
    }
}

// (hann(2n), hann(2n+1)) for n in [0,512), from the 257-entry quarter table.
__device__ __forceinline__ float2 hann_pair(const float2* __restrict__ ph, int n)
{
    const bool mir = n > 256;
    const int  m   = mir ? 512 - n : n;
    const float2 cs = ph[m];
    const float c = mir ? -cs.x : cs.x;
    const float s = cs.y;
    const float w0 = 1.0f - c*c;
    const float c2 = 2.0f*c*c - 1.0f;
    const float s2 = 2.0f*c*s;
    const float w1 = 0.5f - 0.5f*(c2*CDLT - s2*SDLT);
    return make_float2(w0, w1);
}

__global__ __launch_bounds__(256) void zero_seams(float* __restrict__ out)
{
    const int total = NB * (TILES + 1) * 768;
    for (int id = blockIdx.x * 256 + threadIdx.x; id < total; id += gridDim.x * 256) {
        const int q = id % 768;
        const int r = id / 768;
        const int s = r % (TILES + 1);
        const int bb = r / (TILES + 1);
        const int p  = s * SPAN + q;
        const int oi = p - PADT;
        if ((unsigned)oi < (unsigned)OPB) out[(size_t)bb * OPB + oi] = 0.f;
    }
}

__global__ __launch_bounds__(256, 4) void istft16(
    const float* __restrict__ sr, const float* __restrict__ si,
    float* __restrict__ out)
{
    __shared__ uint2  stile[NPAIR * FSTRIDE];  // 36928 B
    __shared__ float2 ph[257];                 //  2056 B -> 38984 B, 4 blocks/CU

    const int tid = threadIdx.x;
    const int bid = blockIdx.x;
    const int nwg = NB * TILES;                           // 4096
    const int swz = (bid & 7) * (nwg >> 3) + (bid >> 3);  // XCD-chunked
    const int b    = swz / TILES;
    const int tile = swz % TILES;
    const int j0   = tile * FR;

    // ---- staging loads first (latency overlaps trig) ----
    const size_t gbase = (size_t)b * NBINS * TFR + (size_t)j0;
    const size_t gaA = gbase + (size_t)tid * TFR;
    const size_t gaB = gbase + (size_t)(512 - tid) * TFR;
    float4 rA0 = *(const float4*)(sr + gaA);
    float4 rA1 = *(const float4*)(sr + gaA + 4);
    float4 rA2 = *(const float4*)(sr + gaA + 8);
    float4 rA3 = *(const float4*)(sr + gaA + 12);
    float4 iA0 = *(const float4*)(si + gaA);
    float4 iA1 = *(const float4*)(si + gaA + 4);
    float4 iA2 = *(const float4*)(si + gaA + 8);
    float4 iA3 = *(const float4*)(si + gaA + 12);
    float4 rB0 = *(const float4*)(sr + gaB);
    float4 rB1 = *(const float4*)(sr + gaB + 4);
    float4 rB2 = *(const float4*)(sr + gaB + 8);
    float4 rB3 = *(const float4*)(sr + gaB + 12);
    float4 iB0 = *(const float4*)(si + gaB);
    float4 iB1 = *(const float4*)(si + gaB + 4);
    float4 iB2 = *(const float4*)(si + gaB + 8);
    float4 iB3 = *(const float4*)(si + gaB + 12);

    if (tid == 0) {
        // irfft ignores Im of bins 0 and 512
        const float4 z4 = make_float4(0.f,0.f,0.f,0.f);
        iA0=iA1=iA2=iA3=z4; iB0=iB1=iB2=iB3=z4;
        // bin 256: Z[256] = conj(X[256]) * SSC, pack frame pairs directly
        const size_t gaC = gbase + (size_t)256 * TFR;
        float4 rC0 = *(const float4*)(sr + gaC);
        float4 rC1 = *(const float4*)(sr + gaC + 4);
        float4 rC2 = *(const float4*)(sr + gaC + 8);
        float4 rC3 = *(const float4*)(sr + gaC + 12);
        float4 iC0 = *(const float4*)(si + gaC);
        float4 iC1 = *(const float4*)(si + gaC + 4);
        float4 iC2 = *(const float4*)(si + gaC + 8);
        float4 iC3 = *(const float4*)(si + gaC + 12);
        const int pn = QIDX(256);
#define Z256P(P, RC, IC, CA, CB)                                            \
        stile[(P)*FSTRIDE + pn] = pack_pair(                                \
            make_float2(RC.CA * SSC, -IC.CA * SSC),                         \
            make_float2(RC.CB * SSC, -IC.CB * SSC))
        Z256P(0, rC0, iC0, x, y);  Z256P(1, rC0, iC0, z, w);
        Z256P(2, rC1, iC1, x, y);  Z256P(3, rC1, iC1, z, w);
        Z256P(4, rC2, iC2, x, y);  Z256P(5, rC2, iC2, z, w);
        Z256P(6, rC3, iC3, x, y);  Z256P(7, rC3, iC3, z, w);
#undef Z256P
    }

    // ---- twiddle quarter-table ----
    for (int m = tid; m < 257; m += 256) {
        float sv, cv;
        sincosf(TWOPI_1024 * (float)m, &sv, &cv);
        ph[m] = make_float2(cv, sv);
    }

    // ---- half-size trick in registers, paired b64 writes ----
    {
        const float h = 0.5f * SSC;
        float swt, cwt;
        sincosf(TWOPI_1024 * (float)tid, &swt, &cwt);
        const int pk  = QIDX(tid);
        const int pk2 = QIDX(512 - tid);   // tid=0 -> slot 576 (unused)
        // per-frame trick -> (Zk, Zm) as float2 pairs
#define TRICKF(XKX, XKY, XMX, XMY, ZK, ZM) do {                             \
            const float Ex = h*((XKX)+(XMX)), Ey = h*((XKY)-(XMY));         \
            const float Dx = h*((XKX)-(XMX)), Dy = h*((XKY)+(XMY));         \
            const float Ox = Dx*cwt - Dy*swt, Oy = Dx*swt + Dy*cwt;         \
            ZK = make_float2(Ex - Oy, Ey + Ox);                             \
            ZM = make_float2(Ex + Oy, Ox - Ey);                             \
        } while (0)
#define TRICKP(P, RA, IA, RB, IB, CA, CB) do {                              \
            float2 zkA, zmA, zkB, zmB;                                      \
            TRICKF(RA.CA, IA.CA, RB.CA, IB.CA, zkA, zmA);                   \
            TRICKF(RA.CB, IA.CB, RB.CB, IB.CB, zkB, zmB);                   \
            stile[(P)*FSTRIDE + pk]  = pack_pair(zkA, zkB);                 \
            stile[(P)*FSTRIDE + pk2] = pack_pair(zmA, zmB);                 \
        } while (0)
        TRICKP(0, rA0, iA0, rB0, iB0, x, y);
        TRICKP(1, rA0, iA0, rB0, iB0, z, w);
        TRICKP(2, rA1, iA1, rB1, iB1, x, y);
        TRICKP(3, rA1, iA1, rB1, iB1, z, w);
        TRICKP(4, rA2, iA2, rB2, iB2, x, y);
        TRICKP(5, rA2, iA2, rB2, iB2, z, w);
        TRICKP(6, rA3, iA3, rB3, iB3, x, y);
        TRICKP(7, rA3, iA3, rB3, iB3, z, w);
#undef TRICKP
#undef TRICKF
    }
    __syncthreads();                                   // B1

    // ---- 512-pt IFFT: 3 paired radix-8 stages, pair = tid>>5 ----
    {
        const int p  = tid >> 5;
        uint2* row   = &stile[p * FSTRIDE];
        const int i0 = tid & 31;
        fft_stage_pk<64>(row, ph, i0);
        fft_stage_pk<64>(row, ph, i0 + 32);
        __syncthreads();                               // B2
        fft_stage_pk<8>(row, ph, i0);
        fft_stage_pk<8>(row, ph, i0 + 32);
        __syncthreads();                               // B3
        fft_stage_pk<1>(row, ph, i0);
        fft_stage_pk<1>(row, ph, i0 + 32);
        __syncthreads();                               // B4
    }

    // ---- OLA: per pair, b64 read gives zA at n and zB at (n+128)%512.
    // accA = a[p+KK]; accB = a[p+1] (KK=0), tlo ? a[p+2] : a[p] (KK=1).
    const bool tlo = (tid < 128);       // wave-coherent
    const float2 wA0 = hann_pair(ph, tid);
    const float2 wA1 = hann_pair(ph, tid + 256);
    const float2 wB0 = hann_pair(ph, tid + 128);
    const float2 wB1 = tlo ? hann_pair(ph, tid + 384) : hann_pair(ph, tid - 128);
    const int n0 = tid, n1 = tid + 256;
    const int js0 = QIDX(((n0 & 7) << 6) | (n0 & 56) | (n0 >> 6));
    const int js1 = QIDX(((n1 & 7) << 6) | (n1 & 56) | (n1 >> 6));

    float2 a0 = make_float2(0.f,0.f), a1=a0, a2=a0, a3=a0, a4=a0,
           a5 = a0, a6=a0, a7=a0, a8=a0, a9=a0;

#define OLA_PAIR(P, AK0, AK1, ABK0, ABK1_T, ABK1_F) do {                    \
        float2 zA0, zB0, zA1, zB1;                                          \
        unpack_pair(stile[(P)*FSTRIDE + js0], zA0, zB0);                    \
        unpack_pair(stile[(P)*FSTRIDE + js1], zA1, zB1);                    \
        AK0.x += zA0.x * wA0.x;  AK0.y += zA0.y * wA0.y;                    \
        AK1.x += zA1.x * wA1.x;  AK1.y += zA1.y * wA1.y;                    \
        ABK0.x += zB0.x * wB0.x; ABK0.y += zB0.y * wB0.y;                   \
        if (tlo) { ABK1_T.x += zB1.x * wB1.x; ABK1_T.y += zB1.y * wB1.y; }  \
        else     { ABK1_F.x += zB1.x * wB1.x; ABK1_F.y += zB1.y * wB1.y; }  \
    } while (0)

    OLA_PAIR(0, a0, a1, a1, a2, a0);
    OLA_PAIR(1, a1, a2, a2, a3, a1);
    OLA_PAIR(2, a2, a3, a3, a4, a2);
    OLA_PAIR(3, a3, a4, a4, a5, a3);
    OLA_PAIR(4, a4, a5, a5, a6, a4);
    OLA_PAIR(5, a5, a6, a6, a7, a5);
    OLA_PAIR(6, a6, a7, a7, a8, a6);
    OLA_PAIR(7, a7, a8, a8, a9, a7);
#undef OLA_PAIR

    // ---- direct stores (values already env-divided by 1.5) ----
    const size_t ob = (size_t)b * OPB;
    const int pb = tile * SPAN;
#define STORE_SEAM(A, G) do {                                               \
        const int oi_ = pb + 2*(tid + 256*(G)) - PADT;                      \
        if ((unsigned)oi_ < (unsigned)OPB)       atomicAdd(&out[ob + oi_],     A.x); \
        if ((unsigned)(oi_+1) < (unsigned)OPB)   atomicAdd(&out[ob + oi_ + 1], A.y); \
    } while (0)
#define STORE_PLAIN(A, G) do {                                              \
        const int oi_ = pb + 2*(tid + 256*(G)) - PADT;                      \
        *(float2*)(out + ob + oi_) = A;                                     \
    } while (0)

    STORE_SEAM(a0, 0);                   // idx [0,512): head seam
    if (tlo) STORE_SEAM(a1, 1);          // [512,768): head seam
    else     STORE_PLAIN(a1, 1);         // [768,1024): interior
    STORE_PLAIN(a2, 2);
    STORE_PLAIN(a3, 3);
    STORE_PLAIN(a4, 4);
    STORE_PLAIN(a5, 5);
    STORE_PLAIN(a6, 6);
    STORE_PLAIN(a7, 7);                  // up to idx 4096
    STORE_SEAM(a8, 8);                   // [4096,4608): tail seam
    if (tlo) STORE_SEAM(a9, 9);          // [4608,4864): tail seam
#undef STORE_SEAM
#undef STORE_PLAIN
}

// env != 1.5 only within 384 samples of the global edges; rescale those.
__global__ __launch_bounds__(256) void edge_fix(float* __restrict__ out)
{
    const int id = blockIdx.x * 256 + threadIdx.x;   // 768 * NB total
    if (id >= 768 * NB) return;
    const int bb = id / 768;
    const int r  = id % 768;
    const int oi = (r < 384) ? r : (OPB - 768 + r);
    const int p  = oi + PADT;
    int jlo = (p - 768) >> 8; if (jlo < 0) jlo = 0;
    int jhi = p >> 8;         if (jhi > TFR - 1) jhi = TFR - 1;
    float e = 0.f;
    for (int j = jlo; j <= jhi; ++j) {
        const float wv = 0.5f - 0.5f * cosf(TWOPI_1024 * (float)(p - j * HOP));
        e += wv * wv;
    }
    out[(size_t)bb * OPB + oi] *= 1.5f / e;
}

extern "C" void kernel_launch(void* const* d_in, const int* in_sizes, int n_in,
                              void* d_out, int out_size, void* d_ws, size_t ws_size,
                              hipStream_t stream) {
    const float* sr = (const float*)d_in[0];
    const float* si = (const float*)d_in[1];
    float* out = (float*)d_out;

    hipLaunchKernelGGL(zero_seams, dim3(2048), dim3(256), 0, stream, out);
    hipLaunchKernelGGL(istft16, dim3(NB * TILES), dim3(256), 0, stream, sr, si, out);
    hipLaunchKernelGGL(edge_fix, dim3((768 * NB + 255) / 256), dim3(256), 0, stream, out);
}